// Round 1
// baseline (157.975 us; speedup 1.0000x reference)
//
#include <hip/hip_runtime.h>

// rep config: E edges, D_IN = D_OUT = 4, M = 32 channels.
// out[e,o,m] = (sum_i basis[e,o,i] * nf[U[e],i,m]) * ew[e, (o==0?0:1), m]
//
// Mapping: 8 lanes per edge; each lane owns a float4 of 4 channels.
// All loads/stores are 16B-per-lane, coalesced within each 8-lane group.

typedef float f4 __attribute__((ext_vector_type(4)));

__global__ __launch_bounds__(256) void equiv_mm_kernel(
    const float* __restrict__ basis,   // [E,4,4]
    const float* __restrict__ ew,      // [E,2,32]
    const float* __restrict__ nf,      // [N,4,32]
    const int*   __restrict__ U,       // [E]
    float*       __restrict__ out,     // [E,4,32]
    int E)
{
    int gid = blockIdx.x * blockDim.x + threadIdx.x;
    int e = gid >> 3;
    if (e >= E) return;
    int m0 = (gid & 7) << 2;   // channel offset: 0,4,...,28

    int u = U[e];

    // gather source-node features: rows i=0..3, stride 32 floats (=8 f4)
    const f4* xp = (const f4*)(nf + (size_t)u * 128 + m0);
    f4 x0 = xp[0];
    f4 x1 = xp[8];
    f4 x2 = xp[16];
    f4 x3 = xp[24];

    // per-edge 4x4 basis (broadcast across the 8 lanes of this edge)
    const f4* bp = (const f4*)(basis + (size_t)e * 16);
    f4 b0 = bp[0], b1 = bp[1], b2 = bp[2], b3 = bp[3];

    // radial weights: degree 0 (o=0) and degree 1 (o=1..3)
    const f4* wp = (const f4*)(ew + (size_t)e * 64 + m0);
    f4 w0 = wp[0];
    f4 w1 = wp[8];

    f4* op = (f4*)(out + (size_t)e * 128 + m0);
    op[0]  = (b0.x * x0 + b0.y * x1 + b0.z * x2 + b0.w * x3) * w0;
    op[8]  = (b1.x * x0 + b1.y * x1 + b1.z * x2 + b1.w * x3) * w1;
    op[16] = (b2.x * x0 + b2.y * x1 + b2.z * x2 + b2.w * x3) * w1;
    op[24] = (b3.x * x0 + b3.y * x1 + b3.z * x2 + b3.w * x3) * w1;
}

extern "C" void kernel_launch(void* const* d_in, const int* in_sizes, int n_in,
                              void* d_out, int out_size, void* d_ws, size_t ws_size,
                              hipStream_t stream) {
    const float* basis = (const float*)d_in[0];   // [E,4,4]
    const float* ew    = (const float*)d_in[1];   // [E,2,32]
    const float* nf    = (const float*)d_in[2];   // [N,4,32]
    const int*   U     = (const int*)d_in[3];     // [E]
    float* out = (float*)d_out;

    int E = in_sizes[0] / 16;
    long long total = (long long)E * 8;           // 8 lanes per edge
    int block = 256;
    int grid = (int)((total + block - 1) / block);

    equiv_mm_kernel<<<grid, block, 0, stream>>>(basis, ew, nf, U, out, E);
}